// Round 17
// baseline (124.492 us; speedup 1.0000x reference)
//
#include <hip/hip_runtime.h>
#include <hip/hip_bf16.h>
#include <math.h>

#define L_SEQ 2048
#define DIMN  1024
#define NH    16
#define HD    64
#define NB    2
#define NTOK  (NB * L_SEQ)   // 4096

typedef __attribute__((ext_vector_type(8))) short bf16x8;
typedef __attribute__((ext_vector_type(4))) float f32x4;
typedef __attribute__((ext_vector_type(16))) float f32x16;
typedef __attribute__((ext_vector_type(4))) short short4v;
typedef __attribute__((ext_vector_type(2))) unsigned uint32x2;

__device__ __forceinline__ short f2bf(float x) {
  return (short)__bfloat16_as_ushort(__float2bfloat16(x));
}
__device__ __forceinline__ float bf2f(short x) {
  union { unsigned u; float f; } c;
  c.u = ((unsigned)(unsigned short)x) << 16;
  return c.f;
}

// v_cvt_pk_bf16_f32: low16 = bf16(lo), high16 = bf16(hi)
__device__ __forceinline__ unsigned cvt_pk_bf16(float lo, float hi) {
  unsigned r;
  asm("v_cvt_pk_bf16_f32 %0, %1, %2" : "=v"(r) : "v"(lo), "v"(hi));
  return r;
}

// v_permlane32_swap_b32: a[32:63] <-> b[0:31]
__device__ __forceinline__ void permlane32_swap(unsigned& a, unsigned& b) {
  asm volatile("v_permlane32_swap_b32 %0, %1" : "+v"(a), "+v"(b));
}

__device__ __forceinline__ void gload_lds16(const short* gsrc, char* lds_dst) {
  __builtin_amdgcn_global_load_lds(
      (const __attribute__((address_space(1))) void*)gsrc,
      (__attribute__((address_space(3))) void*)lds_dst, 16, 0, 0);
}

// ---------------------------------------------------------------------------
// prep: ONE launch for x-cast + 4 weight transpose+casts (z-switch).
// ---------------------------------------------------------------------------
__global__ __launch_bounds__(256) void prep_k(const float* __restrict__ x,
                                              const float* __restrict__ Wq,
                                              const float* __restrict__ Wk,
                                              const float* __restrict__ Wv,
                                              const float* __restrict__ Wo,
                                              short* __restrict__ xb,
                                              short* __restrict__ Wqt,
                                              short* __restrict__ Wkt,
                                              short* __restrict__ Wvt,
                                              short* __restrict__ Wot) {
  const int tid = threadIdx.x;
  if (blockIdx.z == 0) {
    const int id = blockIdx.x + 16 * blockIdx.y;          // 0..255
#pragma unroll
    for (int rep = 0; rep < 8; ++rep) {
      const size_t i = ((size_t)(id + rep * 256)) * 2048 + tid * 8;
      float4 a = *(const float4*)(x + i);
      float4 b = *(const float4*)(x + i + 4);
      bf16x8 o;
      o[0] = f2bf(a.x); o[1] = f2bf(a.y); o[2] = f2bf(a.z); o[3] = f2bf(a.w);
      o[4] = f2bf(b.x); o[5] = f2bf(b.y); o[6] = f2bf(b.z); o[7] = f2bf(b.w);
      *(bf16x8*)(xb + i) = o;
    }
    return;
  }
  const float* W  = (blockIdx.z == 1) ? Wq : (blockIdx.z == 2) ? Wk
                    : (blockIdx.z == 3) ? Wv : Wo;
  short* Wt = (blockIdx.z == 1) ? Wqt : (blockIdx.z == 2) ? Wkt
              : (blockIdx.z == 3) ? Wvt : Wot;
  __shared__ float s[64][65];
  const int k0 = blockIdx.y * 64, n0 = blockIdx.x * 64;
#pragma unroll
  for (int i = 0; i < 4; ++i) {
    int idx = i * 256 + tid;
    int r = idx >> 4, c = (idx & 15) * 4;
    float4 v = *(const float4*)(W + (size_t)(k0 + r) * DIMN + n0 + c);
    s[r][c] = v.x; s[r][c + 1] = v.y; s[r][c + 2] = v.z; s[r][c + 3] = v.w;
  }
  __syncthreads();
#pragma unroll
  for (int i = 0; i < 4; ++i) {
    int idx = i * 256 + tid;
    int r = idx >> 4, c = (idx & 15) * 4;
    short4v o = { f2bf(s[c][r]), f2bf(s[c + 1][r]), f2bf(s[c + 2][r]), f2bf(s[c + 3][r]) };
    *(short4v*)(Wt + (size_t)(n0 + r) * DIMN + k0 + c) = o;
  }
}

// ---------------------------------------------------------------------------
// transpose V: [B,H,L,D] bf16 -> Vt [B,H,D,L] bf16. Grid (L/64, B*H).
// ---------------------------------------------------------------------------
__global__ __launch_bounds__(256) void vT_k(const short* __restrict__ V,
                                            short* __restrict__ Vt) {
  __shared__ short s[64][72];
  const int tid = threadIdx.x;
  const int bh = blockIdx.y;
  const int l0 = blockIdx.x * 64;
  const int row = tid >> 2, c0 = (tid & 3) * 16;
  const short* Vh = V + (size_t)bh * L_SEQ * HD;
  bf16x8 a = *(const bf16x8*)(Vh + (size_t)(l0 + row) * HD + c0);
  bf16x8 b = *(const bf16x8*)(Vh + (size_t)(l0 + row) * HD + c0 + 8);
#pragma unroll
  for (int j = 0; j < 8; ++j) { s[c0 + j][row] = a[j]; s[c0 + 8 + j][row] = b[j]; }
  __syncthreads();
  short* Vth = Vt + (size_t)bh * HD * L_SEQ;
  bf16x8 o0 = *(const bf16x8*)&s[row][c0];
  bf16x8 o1 = *(const bf16x8*)&s[row][c0 + 8];
  *(bf16x8*)(Vth + (size_t)row * L_SEQ + l0 + c0) = o0;
  *(bf16x8*)(Vth + (size_t)row * L_SEQ + l0 + c0 + 8) = o1;
}

// ---------------------------------------------------------------------------
// bf16 MFMA GEMM, 128x128 tile (QKV projections), bf16 [B,H,L,D] out.
// Round-17: SINGLE 32KB LDS buffer -> 3 blocks/CU (was 2), grid 768 = 3/CU
// exactly, no dispatch tail. Per K-step: stage -> vmcnt(0)+barrier ->
// compute -> barrier. Exposed staging latency is hidden by cross-block
// overlap (3 independent blocks/CU).
// ---------------------------------------------------------------------------
__global__ __launch_bounds__(256) void mm_k(const short* __restrict__ A,
                                            const short* __restrict__ B0,
                                            const short* __restrict__ B1,
                                            const short* __restrict__ B2,
                                            short* __restrict__ C0,
                                            short* __restrict__ C1,
                                            short* __restrict__ C2,
                                            float scale0) {
  __shared__ char smem[32768];   // A 16KB | B 16KB, single buffer
  const int tid  = threadIdx.x;
  const int lane = tid & 63, wv = tid >> 6;
  const int g = lane >> 4, r16 = lane & 15;
  const int wr = wv >> 1, wc = wv & 1;
  const int row0 = blockIdx.y * 128, col0 = blockIdx.x * 128;
  const int z = blockIdx.z;
  const short* Bt = (z == 0) ? B0 : (z == 1 ? B1 : B2);
  const float scale = (z == 0) ? scale0 : 1.0f;

  f32x4 acc[4][4];
#pragma unroll
  for (int mi = 0; mi < 4; ++mi)
#pragma unroll
    for (int ni = 0; ni < 4; ++ni) acc[mi][ni] = (f32x4){0.f, 0.f, 0.f, 0.f};

  auto stage = [&](int kt) {
    const int k0 = kt * 64;
    char* As = smem;
    char* Bs = smem + 16384;
#pragma unroll
    for (int j = 0; j < 4; ++j) {
      const int o = j * 4096 + wv * 1024 + lane * 16;
      const int row = o >> 7;
      const int slot = (o >> 4) & 7;
      const int ksrc = k0 + ((slot ^ (row & 7)) << 3);
      gload_lds16(A  + (size_t)(row0 + row) * DIMN + ksrc, As + j * 4096 + wv * 1024);
      gload_lds16(Bt + (size_t)(col0 + row) * DIMN + ksrc, Bs + j * 4096 + wv * 1024);
    }
  };

  auto compute = [&]() {
    const char* As = smem;
    const char* Bs = smem + 16384;
#pragma unroll
    for (int ks = 0; ks < 2; ++ks) {
      bf16x8 a[4], b[4];
#pragma unroll
      for (int mi = 0; mi < 4; ++mi) {
        const int row = wr * 64 + mi * 16 + r16;
        const int slot = (ks * 4 + g) ^ (row & 7);
        a[mi] = *(const bf16x8*)(As + row * 128 + slot * 16);
      }
#pragma unroll
      for (int ni = 0; ni < 4; ++ni) {
        const int row = wc * 64 + ni * 16 + r16;
        const int slot = (ks * 4 + g) ^ (row & 7);
        b[ni] = *(const bf16x8*)(Bs + row * 128 + slot * 16);
      }
#pragma unroll
      for (int mi = 0; mi < 4; ++mi)
#pragma unroll
        for (int ni = 0; ni < 4; ++ni)
          acc[mi][ni] = __builtin_amdgcn_mfma_f32_16x16x32_bf16(a[mi], b[ni], acc[mi][ni], 0, 0, 0);
    }
  };

  for (int kt = 0; kt < DIMN / 64; ++kt) {
    stage(kt);
    asm volatile("s_waitcnt vmcnt(0)" ::: "memory");
    __builtin_amdgcn_s_barrier();
    __builtin_amdgcn_sched_barrier(0);
    compute();
    __syncthreads();   // all readers done before next stage overwrites
  }

  short* Cp = (z == 0) ? C0 : (z == 1 ? C1 : C2);
#pragma unroll
  for (int mi = 0; mi < 4; ++mi) {
#pragma unroll
    for (int reg = 0; reg < 4; ++reg) {
      const int t = row0 + wr * 64 + mi * 16 + 4 * g + reg;
#pragma unroll
      for (int ni = 0; ni < 4; ++ni) {
        const int n = col0 + wc * 64 + ni * 16 + r16;
        const int b = t >> 11, l = t & (L_SEQ - 1);
        const int h = n >> 6, d = n & 63;
        Cp[(((size_t)(b * NH + h)) * L_SEQ + l) * HD + d] =
            f2bf(acc[mi][ni][reg] * scale);
      }
    }
  }
}

// ---------------------------------------------------------------------------
// 64x128-tile GEMM for the output projection, fp32 out (round-16, unchanged).
// ---------------------------------------------------------------------------
__global__ __launch_bounds__(256) void mm64_k(const short* __restrict__ A,
                                              const short* __restrict__ Bt,
                                              float* __restrict__ C) {
  __shared__ char smem[49152];
  const int tid  = threadIdx.x;
  const int lane = tid & 63, wv = tid >> 6;
  const int g = lane >> 4, r16 = lane & 15;
  const int row0 = blockIdx.y * 64, col0 = blockIdx.x * 128;

  f32x4 acc[4][2];
#pragma unroll
  for (int mi = 0; mi < 4; ++mi)
#pragma unroll
    for (int ni = 0; ni < 2; ++ni) acc[mi][ni] = (f32x4){0.f, 0.f, 0.f, 0.f};

  auto stage = [&](int buf, int kt) {
    const int k0 = kt * 64;
    char* As = smem + buf * 24576;
    char* Bs = As + 8192;
#pragma unroll
    for (int j = 0; j < 2; ++j) {
      const int o = j * 4096 + wv * 1024 + lane * 16;
      const int row = o >> 7;
      const int slot = (o >> 4) & 7;
      const int ksrc = k0 + ((slot ^ (row & 7)) << 3);
      gload_lds16(A + (size_t)(row0 + row) * DIMN + ksrc, As + j * 4096 + wv * 1024);
    }
#pragma unroll
    for (int j = 0; j < 4; ++j) {
      const int o = j * 4096 + wv * 1024 + lane * 16;
      const int row = o >> 7;
      const int slot = (o >> 4) & 7;
      const int ksrc = k0 + ((slot ^ (row & 7)) << 3);
      gload_lds16(Bt + (size_t)(col0 + row) * DIMN + ksrc, Bs + j * 4096 + wv * 1024);
    }
  };

  auto compute = [&](int buf) {
    const char* As = smem + buf * 24576;
    const char* Bs = As + 8192;
#pragma unroll
    for (int ks = 0; ks < 2; ++ks) {
      bf16x8 a[4], b[2];
#pragma unroll
      for (int mi = 0; mi < 4; ++mi) {
        const int row = mi * 16 + r16;
        const int slot = (ks * 4 + g) ^ (row & 7);
        a[mi] = *(const bf16x8*)(As + row * 128 + slot * 16);
      }
#pragma unroll
      for (int ni = 0; ni < 2; ++ni) {
        const int row = wv * 32 + ni * 16 + r16;
        const int slot = (ks * 4 + g) ^ (row & 7);
        b[ni] = *(const bf16x8*)(Bs + row * 128 + slot * 16);
      }
#pragma unroll
      for (int mi = 0; mi < 4; ++mi)
#pragma unroll
        for (int ni = 0; ni < 2; ++ni)
          acc[mi][ni] = __builtin_amdgcn_mfma_f32_16x16x32_bf16(a[mi], b[ni], acc[mi][ni], 0, 0, 0);
    }
  };

  stage(0, 0);
  __syncthreads();
  int cur = 0;
  for (int kt = 0; kt < DIMN / 64 - 1; ++kt) {
    stage(cur ^ 1, kt + 1);
    compute(cur);
    __syncthreads();
    cur ^= 1;
  }
  compute(cur);

#pragma unroll
  for (int mi = 0; mi < 4; ++mi) {
#pragma unroll
    for (int reg = 0; reg < 4; ++reg) {
      const int t = row0 + mi * 16 + 4 * g + reg;
#pragma unroll
      for (int ni = 0; ni < 2; ++ni) {
        const int n = col0 + wv * 32 + ni * 16 + r16;
        C[(size_t)t * DIMN + n] = acc[mi][ni][reg];
      }
    }
  }
}

// ---------------------------------------------------------------------------
// Flash attention — round-10 structure, s_setprio REMOVED (A/B: suspected
// regalloc mov-bloat source; everything else byte-identical).
// ---------------------------------------------------------------------------
__global__ __launch_bounds__(256) void attn_k(const short* __restrict__ Q,
                                              const short* __restrict__ K,
                                              const short* __restrict__ Vt,
                                              short* __restrict__ Op0,
                                              short* __restrict__ Op1,
                                              float* __restrict__ Lp) {
  __shared__ char kv[2][16384];                   // [buf][ K 8KB | Vt 8KB ]

  const int tid  = threadIdx.x;
  const int wave = tid >> 6, lane = tid & 63;
  const int h = lane >> 5, r32 = lane & 31;

  const int id = blockIdx.x + 32 * blockIdx.y;    // 0..1023
  const int j8 = id >> 3;                         // 0..127
  const int bh = (id & 7) * 4 + (j8 >> 5);        // head
  const int qtile = (j8 >> 1) & 15;
  const int split = j8 & 1;

  const int qbase = qtile * 128 + wave * 32;
  const int dtile = qtile * 2 + (wave >> 1);
  const int qg = qbase + r32;
  const int kbase = split * 16;

  const short* Qh  = Q  + (size_t)bh * L_SEQ * HD;
  const short* Kh  = K  + (size_t)bh * L_SEQ * HD;
  const short* Vth = Vt + (size_t)bh * HD * L_SEQ;

  bf16x8 qv[4];
#pragma unroll
  for (int ks = 0; ks < 4; ++ks)
    qv[ks] = *(const bf16x8*)(Qh + (size_t)qg * HD + ks * 16 + 8 * h);

  float lsum = 0.f;
  f32x16 o32[2];
#pragma unroll
  for (int db = 0; db < 2; ++db)
#pragma unroll
    for (int r = 0; r < 16; ++r) o32[db][r] = 0.f;

  const int sw = r32 & 7;
  const int rbase = r32 * 128;

  const int si1 = 256 + tid;
  const int row0s = tid >> 3,  c0s = (((tid & 7) ^ (row0s & 7)) << 3);
  const int row1s = si1 >> 3,  c1s = (((si1 & 7) ^ (row1s & 7)) << 3);
  const short* kp0 = Kh + (size_t)(split * 1024 + row0s) * HD + c0s;
  const short* kp1 = Kh + (size_t)(split * 1024 + row1s) * HD + c1s;
  const short* vp0 = Vth + (size_t)row0s * L_SEQ + split * 1024 + c0s;
  const short* vp1 = Vth + (size_t)row1s * L_SEQ + split * 1024 + c1s;
  const int ldo0 = tid * 16, ldo1 = si1 * 16;

  auto stage = [&](char* base) {
    gload_lds16(kp0, base + ldo0);
    gload_lds16(kp1, base + ldo1);
    gload_lds16(vp0, base + 8192 + ldo0);
    gload_lds16(vp1, base + 8192 + ldo1);
    kp0 += 64 * HD;
    kp1 += 64 * HD;
    vp0 += 64;
    vp1 += 64;
  };

  auto compute = [&](const char* Kb, int kt) {
    const char* Vb = Kb + 8192;

    f32x16 sa[2];
#pragma unroll
    for (int kb = 0; kb < 2; ++kb)
#pragma unroll
      for (int r = 0; r < 16; ++r) sa[kb][r] = 0.f;
#pragma unroll
    for (int kb = 0; kb < 2; ++kb)
#pragma unroll
      for (int ks = 0; ks < 4; ++ks) {
        bf16x8 ak = *(const bf16x8*)(Kb + (kb * 32) * 128 + rbase + ((2 * ks + h) ^ sw) * 16);
        sa[kb] = __builtin_amdgcn_mfma_f32_32x32x16_bf16(ak, qv[ks], sa[kb], 0, 0, 0);
      }

    if (kt == dtile) {
      const int tgt = qg - kt * 64;
#pragma unroll
      for (int kb = 0; kb < 2; ++kb)
#pragma unroll
        for (int r = 0; r < 16; ++r)
          if (kb * 32 + (r & 3) + 8 * (r >> 2) + 4 * h == tgt) sa[kb][r] = -INFINITY;
    }

#pragma unroll
    for (int kb = 0; kb < 2; ++kb)
#pragma unroll
      for (int r = 0; r < 16; ++r) sa[kb][r] = __builtin_amdgcn_exp2f(sa[kb][r]);
    float ps = 0.f;
#pragma unroll
    for (int kb = 0; kb < 2; ++kb) {
      float u0 = (sa[kb][0] + sa[kb][1]) + (sa[kb][2] + sa[kb][3]);
      float u1 = (sa[kb][4] + sa[kb][5]) + (sa[kb][6] + sa[kb][7]);
      float u2 = (sa[kb][8] + sa[kb][9]) + (sa[kb][10] + sa[kb][11]);
      float u3 = (sa[kb][12] + sa[kb][13]) + (sa[kb][14] + sa[kb][15]);
      ps += (u0 + u1) + (u2 + u3);
    }
    lsum += ps;

    bf16x8 bp[4];
#pragma unroll
    for (int kk = 0; kk < 4; ++kk) {
      const int kb = kk >> 1, s8 = (kk & 1) * 8;
      unsigned lo0 = cvt_pk_bf16(sa[kb][s8 + 0], sa[kb][s8 + 1]);
      unsigned lo1 = cvt_pk_bf16(sa[kb][s8 + 2], sa[kb][s8 + 3]);
      unsigned hi0 = cvt_pk_bf16(sa[kb][s8 + 4], sa[kb][s8 + 5]);
      unsigned hi1 = cvt_pk_bf16(sa[kb][s8 + 6], sa[kb][s8 + 7]);
      permlane32_swap(lo0, hi0);
      permlane32_swap(lo1, hi1);
      union { unsigned w[4]; bf16x8 v; } u;
      u.w[0] = lo0; u.w[1] = lo1; u.w[2] = hi0; u.w[3] = hi1;
      bp[kk] = u.v;
    }

#pragma unroll
    for (int kk = 0; kk < 4; ++kk)
#pragma unroll
      for (int db = 0; db < 2; ++db) {
        bf16x8 av = *(const bf16x8*)(Vb + (db * 32) * 128 + rbase + ((2 * kk + h) ^ sw) * 16);
        o32[db] = __builtin_amdgcn_mfma_f32_32x32x16_bf16(av, bp[kk], o32[db], 0, 0, 0);
      }
  };

#define STEP(CBUF, SBUF, KT, DO_STAGE)                        \
  do {                                                        \
    asm volatile("s_waitcnt vmcnt(0)" ::: "memory");          \
    __builtin_amdgcn_s_barrier();                             \
    __builtin_amdgcn_sched_barrier(0);                        \
    if (DO_STAGE) stage(SBUF);                                \
    compute(CBUF, KT);                                        \
  } while (0)

  stage(kv[0]);   // first tile
  for (int i = 0; i < 14; i += 2) {
    STEP(kv[0], kv[1], kbase + i,     true);
    STEP(kv[1], kv[0], kbase + i + 1, true);
  }
  STEP(kv[0], kv[1], kbase + 14, true);
  STEP(kv[1], kv[0], kbase + 15, false);
#undef STEP

  lsum += __shfl_xor(lsum, 32);

  short* Opart = split ? Op1 : Op0;
  const size_t rowO = ((size_t)bh * L_SEQ + qg) * HD;
#pragma unroll
  for (int db = 0; db < 2; ++db)
#pragma unroll
    for (int grp = 0; grp < 4; ++grp) {
      const int d0 = db * 32 + grp * 8 + 4 * h;
      uint32x2 ow = { cvt_pk_bf16(o32[db][grp * 4 + 0], o32[db][grp * 4 + 1]),
                      cvt_pk_bf16(o32[db][grp * 4 + 2], o32[db][grp * 4 + 3]) };
      *(uint32x2*)(Opart + rowO + d0) = ow;
    }
  if (h == 0)
    Lp[(size_t)(split * NB * NH + bh) * L_SEQ + qg] = lsum;
}

// ---------------------------------------------------------------------------
// combine: AO[b*L+q][h*64+d] = (Op0 + Op1) / (l0 + l1), bf16 out.
// ---------------------------------------------------------------------------
__global__ __launch_bounds__(256) void combine_k(const short* __restrict__ Op0,
                                                 const short* __restrict__ Op1,
                                                 const float* __restrict__ Lp,
                                                 short* __restrict__ AO) {
  const int idx = blockIdx.x * 256 + threadIdx.x;   // 0..524287
  const int d8 = (idx & 7) * 8;
  const int q  = (idx >> 3) & (L_SEQ - 1);
  const int bh = idx >> 14;                         // 0..31
  const size_t po = ((size_t)bh * L_SEQ + q) * HD + d8;
  bf16x8 p0 = *(const bf16x8*)(Op0 + po);
  bf16x8 p1 = *(const bf16x8*)(Op1 + po);
  const float l0 = Lp[(size_t)bh * L_SEQ + q];
  const float l1 = Lp[(size_t)(NB * NH + bh) * L_SEQ + q];
  const float inv = 1.0f / (l0 + l1);
  const int b = bh >> 4, hh = bh & 15;
  bf16x8 o;
#pragma unroll
  for (int j = 0; j < 8; ++j)
    o[j] = f2bf((bf2f(p0[j]) + bf2f(p1[j])) * inv);
  *(bf16x8*)(AO + ((size_t)(b * L_SEQ + q)) * DIMN + hh * HD + d8) = o;
}

// ---------------------------------------------------------------------------
extern "C" void kernel_launch(void* const* d_in, const int* in_sizes, int n_in,
                              void* d_out, int out_size, void* d_ws, size_t ws_size,
                              hipStream_t stream) {
  const float* x  = (const float*)d_in[0];
  const float* Wq = (const float*)d_in[1];
  const float* Wk = (const float*)d_in[2];
  const float* Wv = (const float*)d_in[3];
  const float* Wo = (const float*)d_in[4];
  float* out = (float*)d_out;

  short* xb  = (short*)d_ws;
  short* Wqt = xb  + (size_t)NTOK * DIMN;
  short* Wkt = Wqt + (size_t)DIMN * DIMN;
  short* Wvt = Wkt + (size_t)DIMN * DIMN;
  short* Wot = Wvt + (size_t)DIMN * DIMN;
  short* Qb  = Wot + (size_t)DIMN * DIMN;
  short* Kb  = Qb  + (size_t)NTOK * DIMN;
  short* Vb  = Kb  + (size_t)NTOK * DIMN;
  short* Vtb = Vb  + (size_t)NTOK * DIMN;
  short* AO  = Vtb + (size_t)NTOK * DIMN;
  float* Lp  = (float*)(AO + (size_t)NTOK * DIMN);   // 2*32*2048 f32 = 512KB
  short* Op0 = xb;   // dead after QKV proj
  short* Op1 = Vb;   // dead after vT_k

  prep_k<<<dim3(16, 16, 5), 256, 0, stream>>>(x, Wq, Wk, Wv, Wo,
                                              xb, Wqt, Wkt, Wvt, Wot);

  // QKV projections; Q pre-scaled by (1/sqrt(D)) * log2(e) for exp2 softmax
  mm_k<<<dim3(DIMN / 128, NTOK / 128, 3), 256, 0, stream>>>(
      xb, Wqt, Wkt, Wvt, Qb, Kb, Vb, 0.125f * 1.4426950408889634f);

  vT_k<<<dim3(L_SEQ / 64, NB * NH), 256, 0, stream>>>(Vb, Vtb);

  // split-K x2 flash attention -> bf16 partials + lsums
  attn_k<<<dim3(32, NB * NH), 256, 0, stream>>>(Qb, Kb, Vtb, Op0, Op1, Lp);

  combine_k<<<2048, 256, 0, stream>>>(Op0, Op1, Lp, AO);

  // output projection: 64x128 tiles, 512 blocks = 2/CU
  mm64_k<<<dim3(DIMN / 128, NTOK / 64), 256, 0, stream>>>(AO, Wot, out);
}

// Round 18
// 120.059 us; speedup vs baseline: 1.0369x; 1.0369x over previous
//
#include <hip/hip_runtime.h>
#include <hip/hip_bf16.h>
#include <math.h>

#define L_SEQ 2048
#define DIMN  1024
#define NH    16
#define HD    64
#define NB    2
#define NTOK  (NB * L_SEQ)   // 4096

typedef __attribute__((ext_vector_type(8))) short bf16x8;
typedef __attribute__((ext_vector_type(4))) float f32x4;
typedef __attribute__((ext_vector_type(16))) float f32x16;
typedef __attribute__((ext_vector_type(4))) short short4v;
typedef __attribute__((ext_vector_type(2))) unsigned uint32x2;

__device__ __forceinline__ short f2bf(float x) {
  return (short)__bfloat16_as_ushort(__float2bfloat16(x));
}
__device__ __forceinline__ float bf2f(short x) {
  union { unsigned u; float f; } c;
  c.u = ((unsigned)(unsigned short)x) << 16;
  return c.f;
}

// v_cvt_pk_bf16_f32: low16 = bf16(lo), high16 = bf16(hi)
__device__ __forceinline__ unsigned cvt_pk_bf16(float lo, float hi) {
  unsigned r;
  asm("v_cvt_pk_bf16_f32 %0, %1, %2" : "=v"(r) : "v"(lo), "v"(hi));
  return r;
}

// v_permlane32_swap_b32: a[32:63] <-> b[0:31]
__device__ __forceinline__ void permlane32_swap(unsigned& a, unsigned& b) {
  asm volatile("v_permlane32_swap_b32 %0, %1" : "+v"(a), "+v"(b));
}

__device__ __forceinline__ void gload_lds16(const short* gsrc, char* lds_dst) {
  __builtin_amdgcn_global_load_lds(
      (const __attribute__((address_space(1))) void*)gsrc,
      (__attribute__((address_space(3))) void*)lds_dst, 16, 0, 0);
}

// ---------------------------------------------------------------------------
// prep: ONE launch for x-cast + 4 weight transpose+casts (z-switch).
// ---------------------------------------------------------------------------
__global__ __launch_bounds__(256) void prep_k(const float* __restrict__ x,
                                              const float* __restrict__ Wq,
                                              const float* __restrict__ Wk,
                                              const float* __restrict__ Wv,
                                              const float* __restrict__ Wo,
                                              short* __restrict__ xb,
                                              short* __restrict__ Wqt,
                                              short* __restrict__ Wkt,
                                              short* __restrict__ Wvt,
                                              short* __restrict__ Wot) {
  const int tid = threadIdx.x;
  if (blockIdx.z == 0) {
    const int id = blockIdx.x + 16 * blockIdx.y;          // 0..255
#pragma unroll
    for (int rep = 0; rep < 8; ++rep) {
      const size_t i = ((size_t)(id + rep * 256)) * 2048 + tid * 8;
      float4 a = *(const float4*)(x + i);
      float4 b = *(const float4*)(x + i + 4);
      bf16x8 o;
      o[0] = f2bf(a.x); o[1] = f2bf(a.y); o[2] = f2bf(a.z); o[3] = f2bf(a.w);
      o[4] = f2bf(b.x); o[5] = f2bf(b.y); o[6] = f2bf(b.z); o[7] = f2bf(b.w);
      *(bf16x8*)(xb + i) = o;
    }
    return;
  }
  const float* W  = (blockIdx.z == 1) ? Wq : (blockIdx.z == 2) ? Wk
                    : (blockIdx.z == 3) ? Wv : Wo;
  short* Wt = (blockIdx.z == 1) ? Wqt : (blockIdx.z == 2) ? Wkt
              : (blockIdx.z == 3) ? Wvt : Wot;
  __shared__ float s[64][65];
  const int k0 = blockIdx.y * 64, n0 = blockIdx.x * 64;
#pragma unroll
  for (int i = 0; i < 4; ++i) {
    int idx = i * 256 + tid;
    int r = idx >> 4, c = (idx & 15) * 4;
    float4 v = *(const float4*)(W + (size_t)(k0 + r) * DIMN + n0 + c);
    s[r][c] = v.x; s[r][c + 1] = v.y; s[r][c + 2] = v.z; s[r][c + 3] = v.w;
  }
  __syncthreads();
#pragma unroll
  for (int i = 0; i < 4; ++i) {
    int idx = i * 256 + tid;
    int r = idx >> 4, c = (idx & 15) * 4;
    short4v o = { f2bf(s[c][r]), f2bf(s[c + 1][r]), f2bf(s[c + 2][r]), f2bf(s[c + 3][r]) };
    *(short4v*)(Wt + (size_t)(n0 + r) * DIMN + k0 + c) = o;
  }
}

// ---------------------------------------------------------------------------
// transpose V: [B,H,L,D] bf16 -> Vt [B,H,D,L] bf16. Grid (L/64, B*H).
// ---------------------------------------------------------------------------
__global__ __launch_bounds__(256) void vT_k(const short* __restrict__ V,
                                            short* __restrict__ Vt) {
  __shared__ short s[64][72];
  const int tid = threadIdx.x;
  const int bh = blockIdx.y;
  const int l0 = blockIdx.x * 64;
  const int row = tid >> 2, c0 = (tid & 3) * 16;
  const short* Vh = V + (size_t)bh * L_SEQ * HD;
  bf16x8 a = *(const bf16x8*)(Vh + (size_t)(l0 + row) * HD + c0);
  bf16x8 b = *(const bf16x8*)(Vh + (size_t)(l0 + row) * HD + c0 + 8);
#pragma unroll
  for (int j = 0; j < 8; ++j) { s[c0 + j][row] = a[j]; s[c0 + 8 + j][row] = b[j]; }
  __syncthreads();
  short* Vth = Vt + (size_t)bh * HD * L_SEQ;
  bf16x8 o0 = *(const bf16x8*)&s[row][c0];
  bf16x8 o1 = *(const bf16x8*)&s[row][c0 + 8];
  *(bf16x8*)(Vth + (size_t)row * L_SEQ + l0 + c0) = o0;
  *(bf16x8*)(Vth + (size_t)row * L_SEQ + l0 + c0 + 8) = o1;
}

// ---------------------------------------------------------------------------
// bf16 MFMA GEMM, 128x128 tile, DOUBLE-buffered (r16 best config).
// bf16 [B,H,L,D] out, scale0 on z==0 (Q).
// ---------------------------------------------------------------------------
__global__ __launch_bounds__(256) void mm_k(const short* __restrict__ A,
                                            const short* __restrict__ B0,
                                            const short* __restrict__ B1,
                                            const short* __restrict__ B2,
                                            short* __restrict__ C0,
                                            short* __restrict__ C1,
                                            short* __restrict__ C2,
                                            float scale0) {
  __shared__ char smem[65536];
  const int tid  = threadIdx.x;
  const int lane = tid & 63, wv = tid >> 6;
  const int g = lane >> 4, r16 = lane & 15;
  const int wr = wv >> 1, wc = wv & 1;
  const int row0 = blockIdx.y * 128, col0 = blockIdx.x * 128;
  const int z = blockIdx.z;
  const short* Bt = (z == 0) ? B0 : (z == 1 ? B1 : B2);
  const float scale = (z == 0) ? scale0 : 1.0f;

  f32x4 acc[4][4];
#pragma unroll
  for (int mi = 0; mi < 4; ++mi)
#pragma unroll
    for (int ni = 0; ni < 4; ++ni) acc[mi][ni] = (f32x4){0.f, 0.f, 0.f, 0.f};

  auto stage = [&](int buf, int kt) {
    const int k0 = kt * 64;
    char* As = smem + buf * 32768;
    char* Bs = As + 16384;
#pragma unroll
    for (int j = 0; j < 4; ++j) {
      const int o = j * 4096 + wv * 1024 + lane * 16;
      const int row = o >> 7;
      const int slot = (o >> 4) & 7;
      const int ksrc = k0 + ((slot ^ (row & 7)) << 3);
      gload_lds16(A  + (size_t)(row0 + row) * DIMN + ksrc, As + j * 4096 + wv * 1024);
      gload_lds16(Bt + (size_t)(col0 + row) * DIMN + ksrc, Bs + j * 4096 + wv * 1024);
    }
  };

  auto compute = [&](int buf) {
    const char* As = smem + buf * 32768;
    const char* Bs = As + 16384;
#pragma unroll
    for (int ks = 0; ks < 2; ++ks) {
      bf16x8 a[4], b[4];
#pragma unroll
      for (int mi = 0; mi < 4; ++mi) {
        const int row = wr * 64 + mi * 16 + r16;
        const int slot = (ks * 4 + g) ^ (row & 7);
        a[mi] = *(const bf16x8*)(As + row * 128 + slot * 16);
      }
#pragma unroll
      for (int ni = 0; ni < 4; ++ni) {
        const int row = wc * 64 + ni * 16 + r16;
        const int slot = (ks * 4 + g) ^ (row & 7);
        b[ni] = *(const bf16x8*)(Bs + row * 128 + slot * 16);
      }
#pragma unroll
      for (int mi = 0; mi < 4; ++mi)
#pragma unroll
        for (int ni = 0; ni < 4; ++ni)
          acc[mi][ni] = __builtin_amdgcn_mfma_f32_16x16x32_bf16(a[mi], b[ni], acc[mi][ni], 0, 0, 0);
    }
  };

  stage(0, 0);
  __syncthreads();
  int cur = 0;
  for (int kt = 0; kt < DIMN / 64 - 1; ++kt) {
    stage(cur ^ 1, kt + 1);
    compute(cur);
    __syncthreads();
    cur ^= 1;
  }
  compute(cur);

  short* Cp = (z == 0) ? C0 : (z == 1 ? C1 : C2);
#pragma unroll
  for (int mi = 0; mi < 4; ++mi) {
#pragma unroll
    for (int reg = 0; reg < 4; ++reg) {
      const int t = row0 + wr * 64 + mi * 16 + 4 * g + reg;
#pragma unroll
      for (int ni = 0; ni < 4; ++ni) {
        const int n = col0 + wc * 64 + ni * 16 + r16;
        const int b = t >> 11, l = t & (L_SEQ - 1);
        const int h = n >> 6, d = n & 63;
        Cp[(((size_t)(b * NH + h)) * L_SEQ + l) * HD + d] =
            f2bf(acc[mi][ni][reg] * scale);
      }
    }
  }
}

// ---------------------------------------------------------------------------
// 64x128-tile GEMM for the output projection, fp32 out (round-16, unchanged).
// ---------------------------------------------------------------------------
__global__ __launch_bounds__(256) void mm64_k(const short* __restrict__ A,
                                              const short* __restrict__ Bt,
                                              float* __restrict__ C) {
  __shared__ char smem[49152];
  const int tid  = threadIdx.x;
  const int lane = tid & 63, wv = tid >> 6;
  const int g = lane >> 4, r16 = lane & 15;
  const int row0 = blockIdx.y * 64, col0 = blockIdx.x * 128;

  f32x4 acc[4][2];
#pragma unroll
  for (int mi = 0; mi < 4; ++mi)
#pragma unroll
    for (int ni = 0; ni < 2; ++ni) acc[mi][ni] = (f32x4){0.f, 0.f, 0.f, 0.f};

  auto stage = [&](int buf, int kt) {
    const int k0 = kt * 64;
    char* As = smem + buf * 24576;
    char* Bs = As + 8192;
#pragma unroll
    for (int j = 0; j < 2; ++j) {
      const int o = j * 4096 + wv * 1024 + lane * 16;
      const int row = o >> 7;
      const int slot = (o >> 4) & 7;
      const int ksrc = k0 + ((slot ^ (row & 7)) << 3);
      gload_lds16(A + (size_t)(row0 + row) * DIMN + ksrc, As + j * 4096 + wv * 1024);
    }
#pragma unroll
    for (int j = 0; j < 4; ++j) {
      const int o = j * 4096 + wv * 1024 + lane * 16;
      const int row = o >> 7;
      const int slot = (o >> 4) & 7;
      const int ksrc = k0 + ((slot ^ (row & 7)) << 3);
      gload_lds16(Bt + (size_t)(col0 + row) * DIMN + ksrc, Bs + j * 4096 + wv * 1024);
    }
  };

  auto compute = [&](int buf) {
    const char* As = smem + buf * 24576;
    const char* Bs = As + 8192;
#pragma unroll
    for (int ks = 0; ks < 2; ++ks) {
      bf16x8 a[4], b[2];
#pragma unroll
      for (int mi = 0; mi < 4; ++mi) {
        const int row = mi * 16 + r16;
        const int slot = (ks * 4 + g) ^ (row & 7);
        a[mi] = *(const bf16x8*)(As + row * 128 + slot * 16);
      }
#pragma unroll
      for (int ni = 0; ni < 2; ++ni) {
        const int row = wv * 32 + ni * 16 + r16;
        const int slot = (ks * 4 + g) ^ (row & 7);
        b[ni] = *(const bf16x8*)(Bs + row * 128 + slot * 16);
      }
#pragma unroll
      for (int mi = 0; mi < 4; ++mi)
#pragma unroll
        for (int ni = 0; ni < 2; ++ni)
          acc[mi][ni] = __builtin_amdgcn_mfma_f32_16x16x32_bf16(a[mi], b[ni], acc[mi][ni], 0, 0, 0);
    }
  };

  stage(0, 0);
  __syncthreads();
  int cur = 0;
  for (int kt = 0; kt < DIMN / 64 - 1; ++kt) {
    stage(cur ^ 1, kt + 1);
    compute(cur);
    __syncthreads();
    cur ^= 1;
  }
  compute(cur);

#pragma unroll
  for (int mi = 0; mi < 4; ++mi) {
#pragma unroll
    for (int reg = 0; reg < 4; ++reg) {
      const int t = row0 + mi * 16 + 4 * g + reg;
#pragma unroll
      for (int ni = 0; ni < 2; ++ni) {
        const int n = col0 + wv * 32 + ni * 16 + r16;
        C[(size_t)t * DIMN + n] = acc[mi][ni][reg];
      }
    }
  }
}

// ---------------------------------------------------------------------------
// Flash attention — round-17 version (r10 structure, setprio-less; best
// measured 56.2-56.6 us). 32x32x16 MFMA, swapped operands, fixed-max exp2
// softmax, in-register P. Split-K x2, 2-buffer pipeline, XCD remap.
// ---------------------------------------------------------------------------
__global__ __launch_bounds__(256) void attn_k(const short* __restrict__ Q,
                                              const short* __restrict__ K,
                                              const short* __restrict__ Vt,
                                              short* __restrict__ Op0,
                                              short* __restrict__ Op1,
                                              float* __restrict__ Lp) {
  __shared__ char kv[2][16384];                   // [buf][ K 8KB | Vt 8KB ]

  const int tid  = threadIdx.x;
  const int wave = tid >> 6, lane = tid & 63;
  const int h = lane >> 5, r32 = lane & 31;

  const int id = blockIdx.x + 32 * blockIdx.y;    // 0..1023
  const int j8 = id >> 3;                         // 0..127
  const int bh = (id & 7) * 4 + (j8 >> 5);        // head
  const int qtile = (j8 >> 1) & 15;
  const int split = j8 & 1;

  const int qbase = qtile * 128 + wave * 32;
  const int dtile = qtile * 2 + (wave >> 1);
  const int qg = qbase + r32;
  const int kbase = split * 16;

  const short* Qh  = Q  + (size_t)bh * L_SEQ * HD;
  const short* Kh  = K  + (size_t)bh * L_SEQ * HD;
  const short* Vth = Vt + (size_t)bh * HD * L_SEQ;

  bf16x8 qv[4];
#pragma unroll
  for (int ks = 0; ks < 4; ++ks)
    qv[ks] = *(const bf16x8*)(Qh + (size_t)qg * HD + ks * 16 + 8 * h);

  float lsum = 0.f;
  f32x16 o32[2];
#pragma unroll
  for (int db = 0; db < 2; ++db)
#pragma unroll
    for (int r = 0; r < 16; ++r) o32[db][r] = 0.f;

  const int sw = r32 & 7;
  const int rbase = r32 * 128;

  const int si1 = 256 + tid;
  const int row0s = tid >> 3,  c0s = (((tid & 7) ^ (row0s & 7)) << 3);
  const int row1s = si1 >> 3,  c1s = (((si1 & 7) ^ (row1s & 7)) << 3);
  const short* kp0 = Kh + (size_t)(split * 1024 + row0s) * HD + c0s;
  const short* kp1 = Kh + (size_t)(split * 1024 + row1s) * HD + c1s;
  const short* vp0 = Vth + (size_t)row0s * L_SEQ + split * 1024 + c0s;
  const short* vp1 = Vth + (size_t)row1s * L_SEQ + split * 1024 + c1s;
  const int ldo0 = tid * 16, ldo1 = si1 * 16;

  auto stage = [&](char* base) {
    gload_lds16(kp0, base + ldo0);
    gload_lds16(kp1, base + ldo1);
    gload_lds16(vp0, base + 8192 + ldo0);
    gload_lds16(vp1, base + 8192 + ldo1);
    kp0 += 64 * HD;
    kp1 += 64 * HD;
    vp0 += 64;
    vp1 += 64;
  };

  auto compute = [&](const char* Kb, int kt) {
    const char* Vb = Kb + 8192;

    f32x16 sa[2];
#pragma unroll
    for (int kb = 0; kb < 2; ++kb)
#pragma unroll
      for (int r = 0; r < 16; ++r) sa[kb][r] = 0.f;
#pragma unroll
    for (int kb = 0; kb < 2; ++kb)
#pragma unroll
      for (int ks = 0; ks < 4; ++ks) {
        bf16x8 ak = *(const bf16x8*)(Kb + (kb * 32) * 128 + rbase + ((2 * ks + h) ^ sw) * 16);
        sa[kb] = __builtin_amdgcn_mfma_f32_32x32x16_bf16(ak, qv[ks], sa[kb], 0, 0, 0);
      }

    if (kt == dtile) {
      const int tgt = qg - kt * 64;
#pragma unroll
      for (int kb = 0; kb < 2; ++kb)
#pragma unroll
        for (int r = 0; r < 16; ++r)
          if (kb * 32 + (r & 3) + 8 * (r >> 2) + 4 * h == tgt) sa[kb][r] = -INFINITY;
    }

#pragma unroll
    for (int kb = 0; kb < 2; ++kb)
#pragma unroll
      for (int r = 0; r < 16; ++r) sa[kb][r] = __builtin_amdgcn_exp2f(sa[kb][r]);
    float ps = 0.f;
#pragma unroll
    for (int kb = 0; kb < 2; ++kb) {
      float u0 = (sa[kb][0] + sa[kb][1]) + (sa[kb][2] + sa[kb][3]);
      float u1 = (sa[kb][4] + sa[kb][5]) + (sa[kb][6] + sa[kb][7]);
      float u2 = (sa[kb][8] + sa[kb][9]) + (sa[kb][10] + sa[kb][11]);
      float u3 = (sa[kb][12] + sa[kb][13]) + (sa[kb][14] + sa[kb][15]);
      ps += (u0 + u1) + (u2 + u3);
    }
    lsum += ps;

    bf16x8 bp[4];
#pragma unroll
    for (int kk = 0; kk < 4; ++kk) {
      const int kb = kk >> 1, s8 = (kk & 1) * 8;
      unsigned lo0 = cvt_pk_bf16(sa[kb][s8 + 0], sa[kb][s8 + 1]);
      unsigned lo1 = cvt_pk_bf16(sa[kb][s8 + 2], sa[kb][s8 + 3]);
      unsigned hi0 = cvt_pk_bf16(sa[kb][s8 + 4], sa[kb][s8 + 5]);
      unsigned hi1 = cvt_pk_bf16(sa[kb][s8 + 6], sa[kb][s8 + 7]);
      permlane32_swap(lo0, hi0);
      permlane32_swap(lo1, hi1);
      union { unsigned w[4]; bf16x8 v; } u;
      u.w[0] = lo0; u.w[1] = lo1; u.w[2] = hi0; u.w[3] = hi1;
      bp[kk] = u.v;
    }

#pragma unroll
    for (int kk = 0; kk < 4; ++kk)
#pragma unroll
      for (int db = 0; db < 2; ++db) {
        bf16x8 av = *(const bf16x8*)(Vb + (db * 32) * 128 + rbase + ((2 * kk + h) ^ sw) * 16);
        o32[db] = __builtin_amdgcn_mfma_f32_32x32x16_bf16(av, bp[kk], o32[db], 0, 0, 0);
      }
  };

#define STEP(CBUF, SBUF, KT, DO_STAGE)                        \
  do {                                                        \
    asm volatile("s_waitcnt vmcnt(0)" ::: "memory");          \
    __builtin_amdgcn_s_barrier();                             \
    __builtin_amdgcn_sched_barrier(0);                        \
    if (DO_STAGE) stage(SBUF);                                \
    compute(CBUF, KT);                                        \
  } while (0)

  stage(kv[0]);   // first tile
  for (int i = 0; i < 14; i += 2) {
    STEP(kv[0], kv[1], kbase + i,     true);
    STEP(kv[1], kv[0], kbase + i + 1, true);
  }
  STEP(kv[0], kv[1], kbase + 14, true);
  STEP(kv[1], kv[0], kbase + 15, false);
#undef STEP

  lsum += __shfl_xor(lsum, 32);

  short* Opart = split ? Op1 : Op0;
  const size_t rowO = ((size_t)bh * L_SEQ + qg) * HD;
#pragma unroll
  for (int db = 0; db < 2; ++db)
#pragma unroll
    for (int grp = 0; grp < 4; ++grp) {
      const int d0 = db * 32 + grp * 8 + 4 * h;
      uint32x2 ow = { cvt_pk_bf16(o32[db][grp * 4 + 0], o32[db][grp * 4 + 1]),
                      cvt_pk_bf16(o32[db][grp * 4 + 2], o32[db][grp * 4 + 3]) };
      *(uint32x2*)(Opart + rowO + d0) = ow;
    }
  if (h == 0)
    Lp[(size_t)(split * NB * NH + bh) * L_SEQ + qg] = lsum;
}

// ---------------------------------------------------------------------------
// combine: AO[b*L+q][h*64+d] = (Op0 + Op1) / (l0 + l1), bf16 out.
// ---------------------------------------------------------------------------
__global__ __launch_bounds__(256) void combine_k(const short* __restrict__ Op0,
                                                 const short* __restrict__ Op1,
                                                 const float* __restrict__ Lp,
                                                 short* __restrict__ AO) {
  const int idx = blockIdx.x * 256 + threadIdx.x;   // 0..524287
  const int d8 = (idx & 7) * 8;
  const int q  = (idx >> 3) & (L_SEQ - 1);
  const int bh = idx >> 14;                         // 0..31
  const size_t po = ((size_t)bh * L_SEQ + q) * HD + d8;
  bf16x8 p0 = *(const bf16x8*)(Op0 + po);
  bf16x8 p1 = *(const bf16x8*)(Op1 + po);
  const float l0 = Lp[(size_t)bh * L_SEQ + q];
  const float l1 = Lp[(size_t)(NB * NH + bh) * L_SEQ + q];
  const float inv = 1.0f / (l0 + l1);
  const int b = bh >> 4, hh = bh & 15;
  bf16x8 o;
#pragma unroll
  for (int j = 0; j < 8; ++j)
    o[j] = f2bf((bf2f(p0[j]) + bf2f(p1[j])) * inv);
  *(bf16x8*)(AO + ((size_t)(b * L_SEQ + q)) * DIMN + hh * HD + d8) = o;
}

// ---------------------------------------------------------------------------
extern "C" void kernel_launch(void* const* d_in, const int* in_sizes, int n_in,
                              void* d_out, int out_size, void* d_ws, size_t ws_size,
                              hipStream_t stream) {
  const float* x  = (const float*)d_in[0];
  const float* Wq = (const float*)d_in[1];
  const float* Wk = (const float*)d_in[2];
  const float* Wv = (const float*)d_in[3];
  const float* Wo = (const float*)d_in[4];
  float* out = (float*)d_out;

  short* xb  = (short*)d_ws;
  short* Wqt = xb  + (size_t)NTOK * DIMN;
  short* Wkt = Wqt + (size_t)DIMN * DIMN;
  short* Wvt = Wkt + (size_t)DIMN * DIMN;
  short* Wot = Wvt + (size_t)DIMN * DIMN;
  short* Qb  = Wot + (size_t)DIMN * DIMN;
  short* Kb  = Qb  + (size_t)NTOK * DIMN;
  short* Vb  = Kb  + (size_t)NTOK * DIMN;
  short* Vtb = Vb  + (size_t)NTOK * DIMN;
  short* AO  = Vtb + (size_t)NTOK * DIMN;
  float* Lp  = (float*)(AO + (size_t)NTOK * DIMN);   // 2*32*2048 f32 = 512KB
  short* Op0 = xb;   // dead after QKV proj
  short* Op1 = Vb;   // dead after vT_k

  prep_k<<<dim3(16, 16, 5), 256, 0, stream>>>(x, Wq, Wk, Wv, Wo,
                                              xb, Wqt, Wkt, Wvt, Wot);

  // QKV projections; Q pre-scaled by (1/sqrt(D)) * log2(e) for exp2 softmax
  mm_k<<<dim3(DIMN / 128, NTOK / 128, 3), 256, 0, stream>>>(
      xb, Wqt, Wkt, Wvt, Qb, Kb, Vb, 0.125f * 1.4426950408889634f);

  vT_k<<<dim3(L_SEQ / 64, NB * NH), 256, 0, stream>>>(Vb, Vtb);

  // split-K x2 flash attention -> bf16 partials + lsums
  attn_k<<<dim3(32, NB * NH), 256, 0, stream>>>(Qb, Kb, Vtb, Op0, Op1, Lp);

  combine_k<<<2048, 256, 0, stream>>>(Op0, Op1, Lp, AO);

  // output projection: 64x128 tiles, 512 blocks = 2/CU
  mm64_k<<<dim3(DIMN / 128, NTOK / 64), 256, 0, stream>>>(AO, Wot, out);
}